// Round 9
// baseline (1921.993 us; speedup 1.0000x reference)
//
#include <hip/hip_runtime.h>
#include <hip/hip_bf16.h>
#include <hip/hip_fp16.h>
#include <cstdint>
#include <cstddef>

#define B_   512
#define T_   128
#define D_   512
#define H_   512
#define MID_ 38
#define BOT_ 38
#define S_   26
#define XL_  588   // D + MID + BOT = W_ih row length

typedef unsigned short u16;
typedef __attribute__((ext_vector_type(8))) short bf16x8v;
typedef __attribute__((ext_vector_type(8))) _Float16 f16x8v;
typedef __attribute__((ext_vector_type(8))) unsigned short u16x8;
typedef __attribute__((ext_vector_type(4))) float f32x4v;

__device__ __forceinline__ u16 f2bf_rn(float f){
  unsigned u = __float_as_uint(f);
  return (u16)((u + 0x7fffu + ((u>>16)&1u)) >> 16);
}
__device__ __forceinline__ float bf2f(u16 v){ return __uint_as_float(((unsigned)v)<<16); }
__device__ __forceinline__ u16 f2h_u(float f){ return __half_as_ushort(__float2half(f)); }
__device__ __forceinline__ float h2f_u(u16 u){ return __half2float(__ushort_as_half(u)); }

// branch-free fast transcendentals (v_exp_f32 + v_rcp_f32, ~1e-6 rel err)
__device__ __forceinline__ float fast_tanh(float x){
  return 1.0f - 2.0f*__builtin_amdgcn_rcpf(__expf(2.0f*x) + 1.0f);
}
__device__ __forceinline__ float fast_sig(float x){
  return __builtin_amdgcn_rcpf(1.0f + __expf(-x));
}

// Barrier that drains LDS ops (lgkmcnt) but leaves global loads (vmcnt) in
// flight across the barrier — avoids the s_waitcnt vmcnt(0) drain that
// __syncthreads() forces.  LDS cross-wave hazards stay safe: all ds ops are
// per-wave complete (lgkmcnt 0) before any wave passes the barrier.
__device__ __forceinline__ void lds_barrier(){
  asm volatile("s_waitcnt lgkmcnt(0)" ::: "memory");
  __builtin_amdgcn_sched_barrier(0);
  __builtin_amdgcn_s_barrier();
}

// ---------------------------------------------------------------------------
// fp32 -> 16-bit plane conversion, 512-col chunks, dest ld dld.
// mode 0: hi=bf16, lo=bf16 residual.  mode 3: hi=fp16 only.
// ---------------------------------------------------------------------------
__global__ __launch_bounds__(256) void cvt_plane(
    const float* __restrict__ src, int ld, int rows, int padrows, int dld,
    u16* __restrict__ hi, u16* __restrict__ lo, int mode)
{
  const int n4 = padrows*128;
  for (int i = blockIdx.x*256 + threadIdx.x; i < n4; i += gridDim.x*256){
    const int row = i >> 7, c4 = (i & 127)*4;
    float4 v = make_float4(0.f,0.f,0.f,0.f);
    if (row < rows) v = *(const float4*)&src[(size_t)row*ld + c4];
    ushort4 h;
    if (mode == 3){
      h.x=f2h_u(v.x); h.y=f2h_u(v.y); h.z=f2h_u(v.z); h.w=f2h_u(v.w);
    } else {
      h.x=f2bf_rn(v.x); h.y=f2bf_rn(v.y); h.z=f2bf_rn(v.z); h.w=f2bf_rn(v.w);
    }
    *(ushort4*)&hi[(size_t)row*dld + c4] = h;
    if (mode == 0){
      ushort4 l;
      l.x=f2bf_rn(v.x-bf2f(h.x)); l.y=f2bf_rn(v.y-bf2f(h.y));
      l.z=f2bf_rn(v.z-bf2f(h.z)); l.w=f2bf_rn(v.w-bf2f(h.w));
      *(ushort4*)&lo[(size_t)row*dld + c4] = l;
    }
  }
}

// token-column tables, transposed for coalesced epilogue reads
__global__ __launch_bounds__(256) void build_tokT(
    const float* __restrict__ Wih, float* __restrict__ WmT, float* __restrict__ WbT)
{
  int i = blockIdx.x*256 + threadIdx.x;   // over 38*2048
  if (i < MID_*2048){
    int c = i >> 11, j = i & 2047;
    WmT[i] = Wih[(size_t)j*XL_ + 512 + c];
    WbT[i] = Wih[(size_t)j*XL_ + 512 + MID_ + c];
  }
}

// bcombF[0:512] = b_h2h; bcombF[512+j] = b_ih[j] + b_hh[j]
__global__ __launch_bounds__(256) void bcomb_kernel(
    const float* __restrict__ bh2h, const float* __restrict__ bih,
    const float* __restrict__ bhh, float* __restrict__ o)
{
  int i = blockIdx.x*256 + threadIdx.x;
  if (i < 512) o[i] = bh2h[i];
  else if (i < 2560) o[i] = bih[i-512] + bhh[i-512];
}

// ---------------------------------------------------------------------------
// proj GEMM, XCD-aware 1D grid (2048 blocks), raw-barrier pipeline.
// A = batch_H fp32 -> fp16 conversion fused in staging; bn==0 blocks
// side-write fp16 A to bHh.  B = Wi2h fp16.  C = fp16 projh via LDS bounce.
// ---------------------------------------------------------------------------
__global__ __launch_bounds__(256) void gemm_proj(
    const float* __restrict__ A, const u16* __restrict__ Bh,
    u16* __restrict__ bHh, u16* __restrict__ projh)
{
  extern __shared__ char smem[];
  constexpr int STR = 40;
  short* As = (short*)smem;                  // [128][STR]
  short* Bs = As + 128*STR;
  const int tid=threadIdx.x;
  const int n = blockIdx.x;
  const int x = n & 7, q = n >> 3;
  const int bn = (q & 3) * 128;
  const int bm = ((q >> 2)*8 + x) * 128;
  const int w=tid>>6, lane=tid&63, wr=w>>1, wc=w&1;
  const bool wrA = ((q & 3) == 0);

  f32x4v acc[4][4];
#pragma unroll
  for (int i=0;i<4;i++)
#pragma unroll
    for (int j=0;j<4;j++) acc[i][j] = (f32x4v){0.f,0.f,0.f,0.f};

  float4 fa[2][2];
  u16x8 rb[2];
  auto load = [&](int it){
    const int kk = it<<5;
#pragma unroll
    for (int L=0; L<2; L++){
      int t=L*256+tid, row=t>>2, c=(t&3)*8;
      const float* p = &A[(size_t)(bm+row)*512 + kk + c];
      fa[L][0] = *(const float4*)p;
      fa[L][1] = *(const float4*)(p+4);
      rb[L] = *(const u16x8*)&Bh[(size_t)(bn+row)*512 + kk + c];
    }
  };
  load(0);

  for (int it=0; it<16; ++it){
    const int kk = it<<5;
#pragma unroll
    for (int L=0; L<2; L++){
      int t=L*256+tid, row=t>>2, c=(t&3)*8;
      u16x8 hv;
      hv[0]=f2h_u(fa[L][0].x); hv[1]=f2h_u(fa[L][0].y);
      hv[2]=f2h_u(fa[L][0].z); hv[3]=f2h_u(fa[L][0].w);
      hv[4]=f2h_u(fa[L][1].x); hv[5]=f2h_u(fa[L][1].y);
      hv[6]=f2h_u(fa[L][1].z); hv[7]=f2h_u(fa[L][1].w);
      *(u16x8*)&As[row*STR+c] = hv;
      if (wrA) *(u16x8*)&bHh[(size_t)(bm+row)*512 + kk + c] = hv;
      *(u16x8*)&Bs[row*STR+c] = rb[L];
    }
    lds_barrier();                     // writes visible; vmcnt NOT drained
    if (it+1 < 16) load(it+1);         // issue next loads, stay in flight
    const int koff = (lane>>4)*8, mrow = lane&15;
#pragma unroll
    for (int i=0;i<4;i++)
#pragma unroll
      for (int j=0;j<4;j++){
        f16x8v af = *(const f16x8v*)&As[(wr*64+i*16+mrow)*STR + koff];
        f16x8v bf = *(const f16x8v*)&Bs[(wc*64+j*16+mrow)*STR + koff];
        acc[i][j] = __builtin_amdgcn_mfma_f32_16x16x32_f16(af, bf, acc[i][j], 0,0,0);
      }
    lds_barrier();                     // reads complete before next write
  }

  // epilogue: fp16 out via LDS bounce
  const int r0 = (lane>>4)*4, cn = lane&15;
  u16* Ts = (u16*)smem;   // [128][128]
#pragma unroll
  for (int i=0;i<4;i++)
#pragma unroll
    for (int j=0;j<4;j++)
#pragma unroll
      for (int r=0;r<4;r++)
        Ts[(wr*64+i*16+r0+r)*128 + wc*64+j*16+cn] = f2h_u(acc[i][j][r]);
  __syncthreads();
#pragma unroll
  for (int q2=0;q2<8;q2++){
    int idx = q2*256 + tid;
    int row = idx>>4, c8 = (idx&15)*8;
    *(float4*)&projh[(size_t)(bm+row)*512 + bn + c8] = *(const float4*)&Ts[row*128 + c8];
  }
}

// ---------------------------------------------------------------------------
// bf16 MFMA GEMM (hcombo and generator), K = kSteps*32, NT, bf16x2 3-pass,
// raw-barrier pipeline.  SWZ=1: 1-D XCD-aware grid decode (8 bm panels).
// MODE 0: fp32 out + col-bias.  MODE 2: generator out (m->(s,b), n<38, +bias2).
// ---------------------------------------------------------------------------
template<int BM,int BN,int MODE,int SWZ>
__global__ __launch_bounds__(256) void gemm_bf(
    const u16* __restrict__ Ah, const u16* __restrict__ Al, int lda,
    const u16* __restrict__ Bh, const u16* __restrict__ Bl, int ldb,
    float* __restrict__ Cout, int ldc,
    const float* __restrict__ bias2, int npass, int kSteps)
{
  extern __shared__ char smem[];
  constexpr int STR = 40;
  short* As = (short*)smem;                  // [BM][STR]
  short* Bs = As + BM*STR;                   // [BN][STR]
  const int tid=threadIdx.x;
  int bm, bn;
  if constexpr (SWZ==1){
    const int n = blockIdx.x;                // 1-D grid, 8 bm panels
    const int x = n & 7, q = n >> 3;
    bm = (q & 7) * BM;
    bn = ((q >> 3)*8 + x) * BN;              // all bm-blocks of a bn panel -> same XCD
  } else {
    bm = blockIdx.y*BM; bn = blockIdx.x*BN;
  }
  const int w=tid>>6, lane=tid&63, wr=w>>1, wc=w&1;
  constexpr int WM=BM/2, WN=BN/2, FM=WM/16, FN=WN/16;
  constexpr int LA=BM/64, LB=BN/64;
  const int nIter = npass*kSteps;

  f32x4v acc[FM][FN];
#pragma unroll
  for (int i=0;i<FM;i++)
#pragma unroll
    for (int j=0;j<FN;j++) acc[i][j] = (f32x4v){0.f,0.f,0.f,0.f};

  u16x8 ra[LA], rb[LB];
  auto load = [&](int it){
    const int pass = it/kSteps, kk = (it%kSteps)<<5;
    const u16* Ap = (pass==2)?Al:Ah;
    const u16* Bp = (pass==1)?Bl:Bh;
#pragma unroll
    for (int L=0; L<LA; L++){
      int t=L*256+tid, row=t>>2, c=(t&3)*8;
      ra[L] = *(const u16x8*)&Ap[(size_t)(bm+row)*lda + kk + c];
    }
#pragma unroll
    for (int L=0; L<LB; L++){
      int t=L*256+tid, row=t>>2, c=(t&3)*8;
      rb[L] = *(const u16x8*)&Bp[(size_t)(bn+row)*ldb + kk + c];
    }
  };
  load(0);

  for (int it=0; it<nIter; ++it){
#pragma unroll
    for (int L=0; L<LA; L++){ int t=L*256+tid; *(u16x8*)&As[(t>>2)*STR+(t&3)*8] = ra[L]; }
#pragma unroll
    for (int L=0; L<LB; L++){ int t=L*256+tid; *(u16x8*)&Bs[(t>>2)*STR+(t&3)*8] = rb[L]; }
    lds_barrier();                     // writes visible; vmcnt in flight
    if (it+1 < nIter) load(it+1);
    const int koff = (lane>>4)*8, mrow = lane&15;
#pragma unroll
    for (int i=0;i<FM;i++)
#pragma unroll
      for (int j=0;j<FN;j++){
        bf16x8v af = *(const bf16x8v*)&As[(wr*WM+i*16+mrow)*STR + koff];
        bf16x8v bf = *(const bf16x8v*)&Bs[(wc*WN+j*16+mrow)*STR + koff];
        acc[i][j] = __builtin_amdgcn_mfma_f32_16x16x32_bf16(af, bf, acc[i][j], 0,0,0);
      }
    lds_barrier();                     // reads done before next write
  }

  const int r0 = (lane>>4)*4, cn = lane&15;
  if constexpr (MODE==2){
#pragma unroll
    for (int i=0;i<FM;i++)
#pragma unroll
      for (int j=0;j<FN;j++)
#pragma unroll
        for (int r=0;r<4;r++){
          int m = bm + wr*WM + i*16 + r0 + r;       // m = s*512 + b
          int n2 = bn + wc*WN + j*16 + cn;
          if (n2 < MID_){
            int s = m >> 9, b = m & 511;
            Cout[((size_t)b*S_ + s)*MID_ + n2] = acc[i][j][r] + bias2[n2];
          }
        }
  } else {
#pragma unroll
    for (int i=0;i<FM;i++)
#pragma unroll
      for (int j=0;j<FN;j++)
#pragma unroll
        for (int r=0;r<4;r++){
          int row = bm + wr*WM + i*16 + r0 + r;
          int col = bn + wc*WN + j*16 + cn;
          float v = acc[i][j][r];
          if (bias2) v += bias2[col];
          Cout[(size_t)row*ldc + col] = v;
        }
  }
}

// ---------------------------------------------------------------------------
// Fused attention, 1024 threads (16 waves):
//   pp from combo[b][0:512] (fp32, ld 2560)
//   e[t] = sum_h Ws[h]*fast_tanh(projh[b,t,h]+pp[h]); softmax over t;
//   ctx[b,d] = sum_t alpha[t]*bHh[b,t,d] -> ctx hi/lo planes.
// ---------------------------------------------------------------------------
__global__ __launch_bounds__(1024) void attn_kernel(
    const u16* __restrict__ projh, const float* __restrict__ combo,
    const float* __restrict__ Wscore, const u16* __restrict__ bHh,
    u16* __restrict__ ctx_hi, u16* __restrict__ ctx_lo)
{
  __shared__ float s_e[T_];
  __shared__ float s_red[32];
  __shared__ float s_part[16][D_];
  const int tid=threadIdx.x, b=blockIdx.x, wave=tid>>6, lane=tid&63;

  float pv[8], wv[8];
  {
    const float* pprow = combo + (size_t)b*2560;
    float4 p0=*(const float4*)&pprow[lane*8], p1=*(const float4*)&pprow[lane*8+4];
    float4 w0=*(const float4*)&Wscore[lane*8], w1=*(const float4*)&Wscore[lane*8+4];
    pv[0]=p0.x;pv[1]=p0.y;pv[2]=p0.z;pv[3]=p0.w;pv[4]=p1.x;pv[5]=p1.y;pv[6]=p1.z;pv[7]=p1.w;
    wv[0]=w0.x;wv[1]=w0.y;wv[2]=w0.z;wv[3]=w0.w;wv[4]=w1.x;wv[5]=w1.y;wv[6]=w1.z;wv[7]=w1.w;
  }
  // e-phase: wave w handles t = w, w+16, ... (8 rows); 2-deep pipeline
  {
    const u16* base = projh + (size_t)b*T_*H_ + lane*8;
    u16x8 cur = *(const u16x8*)(base + (size_t)wave*H_);
    for (int t=wave; t<T_; t+=16){
      u16x8 nxt;
      if (t+16 < T_) nxt = *(const u16x8*)(base + (size_t)(t+16)*H_);
      float acc = 0.f;
#pragma unroll
      for (int j=0;j<8;j++) acc += wv[j]*fast_tanh(h2f_u(cur[j]) + pv[j]);
#pragma unroll
      for (int o=32;o>0;o>>=1) acc += __shfl_down(acc,o);
      if (lane==0) s_e[t] = acc;
      cur = nxt;
    }
  }
  __syncthreads();
  // softmax over s_e[0..127]
  float v = (tid < T_) ? s_e[tid] : -INFINITY;
  float m = v;
#pragma unroll
  for (int o=32;o>0;o>>=1) m = fmaxf(m, __shfl_down(m,o));
  if (tid < T_ && lane==0) s_red[wave] = m;      // waves 0,1 write
  __syncthreads();
  m = fmaxf(s_red[0], s_red[1]);
  float p = (tid < T_) ? __expf(v - m) : 0.f;
  float sum = p;
#pragma unroll
  for (int o=32;o>0;o>>=1) sum += __shfl_down(sum,o);
  if (tid < T_ && lane==0) s_red[16+wave] = sum;
  __syncthreads();
  float denom = s_red[16] + s_red[17];
  if (tid < T_) s_e[tid] = p/denom;
  __syncthreads();

  // context: wave w covers t in [8w, 8w+8); lane covers d = lane*8..+7
  const int d0 = lane*8;
  float a[8] = {0,0,0,0,0,0,0,0};
  {
    const u16* base = bHh + (size_t)b*T_*D_ + d0;
    u16x8 cur = *(const u16x8*)(base + (size_t)(wave*8)*D_);
    for (int t=wave*8; t<wave*8+8; ++t){
      u16x8 nxt;
      if (t+1 < wave*8+8) nxt = *(const u16x8*)(base + (size_t)(t+1)*D_);
      const float al = s_e[t];
#pragma unroll
      for (int j=0;j<8;j++) a[j] += al*h2f_u(cur[j]);
      cur = nxt;
    }
  }
  *(float4*)&s_part[wave][d0]   = make_float4(a[0],a[1],a[2],a[3]);
  *(float4*)&s_part[wave][d0+4] = make_float4(a[4],a[5],a[6],a[7]);
  __syncthreads();
  if (tid < D_){
    float vv = s_part[0][tid];
#pragma unroll
    for (int q=1;q<16;q++) vv += s_part[q][tid];
    u16 hh=f2bf_rn(vv), ll=f2bf_rn(vv-bf2f(hh));
    ctx_hi[(size_t)b*512 + tid] = hh;
    ctx_lo[(size_t)b*512 + tid] = ll;
  }
}

// ---------------------------------------------------------------------------
// Fused gates GEMM + LSTM pointwise.  K=512 bf16x2 3-pass, BK=64,
// raw-barrier pipeline, XCD-aware 1-D grid (256 blocks).
// gates = ctx @ W_ih[:,:512]^T + combo[:,512:] (h-part precomputed).
// A (ctx planes) direct-from-global; B via LDS.  B row n = f*16+jj ->
// Bih row f*512+(j0+jj): fragment f holds gate f.  Epilogue: + combo +
// token adds, activations, c/h update; writes h planes + hid planes.
// ---------------------------------------------------------------------------
__global__ __launch_bounds__(256) void gates_lstm(
    const u16* __restrict__ Ah, const u16* __restrict__ Al,     // [512][512]
    const u16* __restrict__ Bh, const u16* __restrict__ Bl,     // [2048][512]
    const float* __restrict__ combo,                            // [512][2560]
    const float* __restrict__ WmT, const float* __restrict__ WbT,
    const int* __restrict__ midtok, const int* __restrict__ bottok,
    float* __restrict__ c,
    u16* __restrict__ hA_hi, u16* __restrict__ hA_lo,
    u16* __restrict__ hid_hi, u16* __restrict__ hid_lo, int s)
{
  constexpr int STR = 72;
  __shared__ short Bs[64*STR];
  const int tid=threadIdx.x, lane=tid&63, w=tid>>6;
  const int n = blockIdx.x;                 // 256 blocks, XCD decode
  const int x = n & 7, q = n >> 3;
  const int bm = (q & 7) * 64;
  const int j0 = ((q >> 3)*8 + x) * 16;     // j-panels of one XCD share Bih
  const int mrow=lane&15, koff=(lane>>4)*8;
  const int arow = bm + w*16 + mrow;
  const int srow = tid>>2, scc=(tid&3)*8;
  const int sbrow = (srow>>4)*512 + j0 + (srow&15);

  f32x4v acc[4];
#pragma unroll
  for (int f=0;f<4;f++) acc[f] = (f32x4v){0.f,0.f,0.f,0.f};

  u16x8 sb0, sb1;
  bf16x8v a0[2], a1[2];
  auto loadB = [&](int it){
    const int pass = it>>3, kk=(it&7)<<6;
    const u16* Bp = (pass==1)?Bl:Bh;
    sb0 = *(const u16x8*)&Bp[(size_t)sbrow*512 + kk + scc];
    sb1 = *(const u16x8*)&Bp[(size_t)sbrow*512 + kk + scc + 32];
  };
  auto loadA0 = [&](int it){
    const int pass = it>>3, kk=(it&7)<<6;
    const u16* Ap = (pass==2)?Al:Ah;
    a0[0] = *(const bf16x8v*)&Ap[(size_t)arow*512 + kk + koff];
    a0[1] = *(const bf16x8v*)&Ap[(size_t)arow*512 + kk + koff + 32];
  };
  auto loadA1 = [&](int it){
    const int pass = it>>3, kk=(it&7)<<6;
    const u16* Ap = (pass==2)?Al:Ah;
    a1[0] = *(const bf16x8v*)&Ap[(size_t)arow*512 + kk + koff];
    a1[1] = *(const bf16x8v*)&Ap[(size_t)arow*512 + kk + koff + 32];
  };

  loadB(0); loadA0(0);
  for (int it=0; it<24; it+=2){
    *(u16x8*)&Bs[srow*STR+scc]    = sb0;
    *(u16x8*)&Bs[srow*STR+scc+32] = sb1;
    lds_barrier();
    if (it+1 < 24){ loadB(it+1); loadA1(it+1); }
#pragma unroll
    for (int f=0;f<4;f++){
      bf16x8v b0 = *(const bf16x8v*)&Bs[(f*16+mrow)*STR + koff];
      bf16x8v b1 = *(const bf16x8v*)&Bs[(f*16+mrow)*STR + koff + 32];
      acc[f] = __builtin_amdgcn_mfma_f32_16x16x32_bf16(a0[0], b0, acc[f], 0,0,0);
      acc[f] = __builtin_amdgcn_mfma_f32_16x16x32_bf16(a0[1], b1, acc[f], 0,0,0);
    }
    lds_barrier();
    if (it+1 >= 24) break;
    *(u16x8*)&Bs[srow*STR+scc]    = sb0;
    *(u16x8*)&Bs[srow*STR+scc+32] = sb1;
    lds_barrier();
    if (it+2 < 24){ loadB(it+2); loadA0(it+2); }
#pragma unroll
    for (int f=0;f<4;f++){
      bf16x8v b0 = *(const bf16x8v*)&Bs[(f*16+mrow)*STR + koff];
      bf16x8v b1 = *(const bf16x8v*)&Bs[(f*16+mrow)*STR + koff + 32];
      acc[f] = __builtin_amdgcn_mfma_f32_16x16x32_bf16(a1[0], b0, acc[f], 0,0,0);
      acc[f] = __builtin_amdgcn_mfma_f32_16x16x32_bf16(a1[1], b1, acc[f], 0,0,0);
    }
    lds_barrier();
  }

  // epilogue: lane holds gates f=0..3 for rows r0..r0+3 (b), col jj
  const int r0=(lane>>4)*4, jj=lane&15, j=j0+jj;
#pragma unroll
  for (int r=0;r<4;r++){
    const int b = bm + w*16 + r0 + r;
    const int mt = midtok[b*26 + s];
    const int bt = bottok[b*26 + s];
    const float* wm = WmT + (size_t)mt*2048;
    const float* wb = WbT + (size_t)bt*2048;
    const float* cb = combo + (size_t)b*2560 + 512;
    float ig = acc[0][r] + cb[j       ] + wm[j       ] + wb[j       ];
    float fg = acc[1][r] + cb[512 + j ] + wm[512 + j ] + wb[512 + j ];
    float gg = acc[2][r] + cb[1024 + j] + wm[1024 + j] + wb[1024 + j];
    float og = acc[3][r] + cb[1536 + j] + wm[1536 + j] + wb[1536 + j];
    ig = fast_sig(ig);
    fg = fast_sig(fg);
    gg = fast_tanh(gg);
    og = fast_sig(og);
    const size_t ci = (size_t)b*512 + j;
    const float cn = fg*c[ci] + ig*gg;
    const float hn = og*fast_tanh(cn);
    c[ci] = cn;
    u16 hh = f2bf_rn(hn), hl = f2bf_rn(hn - bf2f(hh));
    hA_hi[ci] = hh;
    hA_lo[ci] = hl;
    hid_hi[((size_t)s*512 + b)*512 + j] = hh;
    hid_lo[((size_t)s*512 + b)*512 + j] = hl;
  }
}

extern "C" void kernel_launch(void* const* d_in, const int* in_sizes, int n_in,
                              void* d_out, int out_size, void* d_ws, size_t ws_size,
                              hipStream_t stream) {
  const float* bH   = (const float*)d_in[0];
  const int*   midt = (const int*)  d_in[1];
  const int*   bott = (const int*)  d_in[2];
  const float* Wi2h = (const float*)d_in[3];
  const float* Wh2h = (const float*)d_in[4];
  const float* bh2h = (const float*)d_in[5];
  const float* Wsc  = (const float*)d_in[6];
  const float* Wih  = (const float*)d_in[7];
  const float* Whh  = (const float*)d_in[8];
  const float* bih  = (const float*)d_in[9];
  const float* bhh  = (const float*)d_in[10];
  const float* Wgen = (const float*)d_in[11];
  const float* bgen = (const float*)d_in[12];
  float* out = (float*)d_out;

  char* wp = (char*)d_ws;
  u16* projh   = (u16*)wp; wp += (size_t)B_*T_*H_*2;      // 67.1 MB fp16
  u16* bHh     = (u16*)wp; wp += (size_t)B_*T_*D_*2;      // 67.1 MB fp16
  u16* Bh2_hi  = (u16*)wp; wp += (size_t)2560*512*2;      // [W_h2h|W_hh] planes
  u16* Bh2_lo  = (u16*)wp; wp += (size_t)2560*512*2;
  u16* Bih_hi  = (u16*)wp; wp += (size_t)2048*512*2;      // W_ih[:, :512] planes
  u16* Bih_lo  = (u16*)wp; wp += (size_t)2048*512*2;
  u16* Wi2h_h  = (u16*)wp; wp += (size_t)512*512*2;       // fp16
  u16* Wg_hi   = (u16*)wp; wp += (size_t)64*512*2;
  u16* Wg_lo   = (u16*)wp; wp += (size_t)64*512*2;
  u16* ctx_hi  = (u16*)wp; wp += (size_t)B_*512*2;
  u16* ctx_lo  = (u16*)wp; wp += (size_t)B_*512*2;
  u16* hA_hi   = (u16*)wp; wp += (size_t)B_*512*2;
  u16* hA_lo   = (u16*)wp; wp += (size_t)B_*512*2;
  u16* hid_hi  = (u16*)wp; wp += (size_t)S_*B_*H_*2;      // 13.6 MB
  u16* hid_lo  = (u16*)wp; wp += (size_t)S_*B_*H_*2;
  float* combo = (float*)wp; wp += (size_t)B_*2560*4;     // 5.2 MB
  float* c     = (float*)wp; wp += (size_t)B_*H_*4;
  float* bcombF= (float*)wp; wp += (size_t)2560*4;
  float* WmT   = (float*)wp; wp += (size_t)MID_*2048*4;
  float* WbT   = (float*)wp; wp += (size_t)BOT_*2048*4;
  if ((size_t)(wp - (char*)d_ws) > ws_size) return;  // fail loudly

  hipMemsetAsync(hA_hi, 0, (size_t)B_*512*2, stream);
  hipMemsetAsync(hA_lo, 0, (size_t)B_*512*2, stream);
  hipMemsetAsync(c, 0, (size_t)B_*H_*4, stream);

  bcomb_kernel<<<10, 256, 0, stream>>>(bh2h, bih, bhh, bcombF);
  build_tokT<<<(MID_*2048+255)/256, 256, 0, stream>>>(Wih, WmT, WbT);
  cvt_plane<<<64,  256, 0, stream>>>(Wi2h, 512, 512, 512, 512, Wi2h_h, nullptr, 3);
  cvt_plane<<<64,  256, 0, stream>>>(Wh2h, 512, 512, 512, 512, Bh2_hi, Bh2_lo, 0);
  cvt_plane<<<256, 256, 0, stream>>>(Whh, 512, 2048, 2048, 512,
                                     Bh2_hi+(size_t)512*512, Bh2_lo+(size_t)512*512, 0);
  cvt_plane<<<256, 256, 0, stream>>>(Wih, XL_, 2048, 2048, 512, Bih_hi, Bih_lo, 0);
  cvt_plane<<<16,  256, 0, stream>>>(Wgen, 512, MID_, 64, 512, Wg_hi, Wg_lo, 0);

  // proj = fp16( batch_H @ W_i2h^T ), XCD-aware 1D grid, raw-barrier pipeline
  gemm_proj<<<2048, 256, 32768, stream>>>(bH, Wi2h_h, bHh, projh);

  for (int s=0; s<S_; ++s){
    // combo = h @ [W_h2h | W_hh]^T + [b_h2h | b_ih+b_hh]  (bf16x2, N=2560, SWZ)
    gemm_bf<64,64,0,1><<<320, 256, 10240, stream>>>(
        hA_hi, hA_lo, 512, Bh2_hi, Bh2_lo, 512,
        combo, 2560, bcombF, 3, 16);
    attn_kernel<<<B_, 1024, 0, stream>>>(
        projh, combo, Wsc, bHh, ctx_hi, ctx_lo);
    gates_lstm<<<256, 256, 0, stream>>>(
        ctx_hi, ctx_lo, Bih_hi, Bih_lo, combo, WmT, WbT,
        midt, bott, c, hA_hi, hA_lo,
        hid_hi, hid_lo, s);
  }

  // out = hid @ W_gen^T + b_gen  (bf16x2), M = S*B = 13312, N=64 (n<38 kept)
  gemm_bf<64,64,2,0><<<dim3(1,208), 256, 10240, stream>>>(
      hid_hi, hid_lo, 512, Wg_hi, Wg_lo, 512,
      out, 0, bgen, 3, 16);
}

// Round 10
// 1690.283 us; speedup vs baseline: 1.1371x; 1.1371x over previous
//
#include <hip/hip_runtime.h>
#include <hip/hip_bf16.h>
#include <hip/hip_fp16.h>
#include <cstdint>
#include <cstddef>

#define B_   512
#define T_   128
#define D_   512
#define H_   512
#define MID_ 38
#define BOT_ 38
#define S_   26
#define XL_  588   // D + MID + BOT = W_ih row length

typedef unsigned short u16;
typedef __attribute__((ext_vector_type(8))) short bf16x8v;
typedef __attribute__((ext_vector_type(8))) _Float16 f16x8v;
typedef __attribute__((ext_vector_type(8))) unsigned short u16x8;
typedef __attribute__((ext_vector_type(4))) float f32x4v;

__device__ __forceinline__ u16 f2bf_rn(float f){
  unsigned u = __float_as_uint(f);
  return (u16)((u + 0x7fffu + ((u>>16)&1u)) >> 16);
}
__device__ __forceinline__ float bf2f(u16 v){ return __uint_as_float(((unsigned)v)<<16); }
__device__ __forceinline__ u16 f2h_u(float f){ return __half_as_ushort(__float2half(f)); }
__device__ __forceinline__ float h2f_u(u16 u){ return __half2float(__ushort_as_half(u)); }

// branch-free fast transcendentals (v_exp_f32 + v_rcp_f32, ~1e-6 rel err)
__device__ __forceinline__ float fast_tanh(float x){
  return 1.0f - 2.0f*__builtin_amdgcn_rcpf(__expf(2.0f*x) + 1.0f);
}
__device__ __forceinline__ float fast_sig(float x){
  return __builtin_amdgcn_rcpf(1.0f + __expf(-x));
}

// ---------------------------------------------------------------------------
// One-shot setup: all weight conversions + token tables + bias combine,
// flat quad-index space, grid-stride.
// ---------------------------------------------------------------------------
__device__ __forceinline__ void cvt_hilo4(const float* src, u16* hi, u16* lo){
  float4 v = *(const float4*)src;
  ushort4 h, l;
  h.x=f2bf_rn(v.x); h.y=f2bf_rn(v.y); h.z=f2bf_rn(v.z); h.w=f2bf_rn(v.w);
  l.x=f2bf_rn(v.x-bf2f(h.x)); l.y=f2bf_rn(v.y-bf2f(h.y));
  l.z=f2bf_rn(v.z-bf2f(h.z)); l.w=f2bf_rn(v.w-bf2f(h.w));
  *(ushort4*)hi = h; *(ushort4*)lo = l;
}

__global__ __launch_bounds__(256) void setup_all(
    const float* __restrict__ Wi2h, const float* __restrict__ Wh2h,
    const float* __restrict__ Whh,  const float* __restrict__ Wih,
    const float* __restrict__ Wgen, const float* __restrict__ bh2h,
    const float* __restrict__ bih,  const float* __restrict__ bhh,
    u16* __restrict__ Wi2h_h, u16* __restrict__ Bh2_hi, u16* __restrict__ Bh2_lo,
    u16* __restrict__ Bih_hi, u16* __restrict__ Bih_lo,
    u16* __restrict__ Wg_hi,  u16* __restrict__ Wg_lo,
    float* __restrict__ WmT, float* __restrict__ WbT, float* __restrict__ bcombF)
{
  const int Q0=65536, T0=Q0;            // Wi2h -> fp16
  const int T1=T0+65536;                // Wh2h -> Bh2[0:512] hi/lo
  const int T2=T1+262144;               // Whh  -> Bh2[512:2560]
  const int T3=T2+262144;               // Wih[:, :512] -> Bih
  const int T4=T3+8192;                 // Wgen -> Wg (pad 64 rows)
  const int T5=T4+19456;                // token tables (38*512 quads)
  const int T6=T5+640;                  // bcombF
  for (int i = blockIdx.x*256 + threadIdx.x; i < T6; i += gridDim.x*256){
    if (i < T0){
      int row=i>>7, c4=(i&127)*4;
      float4 v = *(const float4*)&Wi2h[(size_t)row*512 + c4];
      ushort4 h; h.x=f2h_u(v.x); h.y=f2h_u(v.y); h.z=f2h_u(v.z); h.w=f2h_u(v.w);
      *(ushort4*)&Wi2h_h[(size_t)row*512 + c4] = h;
    } else if (i < T1){
      int j=i-T0, row=j>>7, c4=(j&127)*4;
      cvt_hilo4(&Wh2h[(size_t)row*512+c4], &Bh2_hi[(size_t)row*512+c4], &Bh2_lo[(size_t)row*512+c4]);
    } else if (i < T2){
      int j=i-T1, row=j>>7, c4=(j&127)*4;
      cvt_hilo4(&Whh[(size_t)row*512+c4],
                &Bh2_hi[(size_t)(512+row)*512+c4], &Bh2_lo[(size_t)(512+row)*512+c4]);
    } else if (i < T3){
      int j=i-T2, row=j>>7, c4=(j&127)*4;
      cvt_hilo4(&Wih[(size_t)row*XL_+c4], &Bih_hi[(size_t)row*512+c4], &Bih_lo[(size_t)row*512+c4]);
    } else if (i < T4){
      int j=i-T3, row=j>>7, c4=(j&127)*4;
      float4 v = make_float4(0.f,0.f,0.f,0.f);
      if (row < MID_) v = *(const float4*)&Wgen[(size_t)row*512 + c4];
      ushort4 h, l;
      h.x=f2bf_rn(v.x); h.y=f2bf_rn(v.y); h.z=f2bf_rn(v.z); h.w=f2bf_rn(v.w);
      l.x=f2bf_rn(v.x-bf2f(h.x)); l.y=f2bf_rn(v.y-bf2f(h.y));
      l.z=f2bf_rn(v.z-bf2f(h.z)); l.w=f2bf_rn(v.w-bf2f(h.w));
      *(ushort4*)&Wg_hi[(size_t)row*512+c4] = h;
      *(ushort4*)&Wg_lo[(size_t)row*512+c4] = l;
    } else if (i < T5){
      int j=i-T4;                    // 38*512
      int c=j>>9, jq=j&511;
#pragma unroll
      for (int u=0;u<4;u++){
        int jj=jq*4+u;
        WmT[(size_t)c*2048+jj] = Wih[(size_t)jj*XL_ + 512 + c];
        WbT[(size_t)c*2048+jj] = Wih[(size_t)jj*XL_ + 512 + MID_ + c];
      }
    } else {
      int j=(i-T5)*4;
#pragma unroll
      for (int u=0;u<4;u++){
        int k=j+u;
        if (k < 512) bcombF[k] = bh2h[k];
        else if (k < 2560) bcombF[k] = bih[k-512] + bhh[k-512];
      }
    }
  }
}

// ---------------------------------------------------------------------------
// proj GEMM, BM=128 BN=64 (32 AGPR acc -> ~5 waves/SIMD), XCD-aware 1D grid
// (4096 blocks): x=n&7 (XCD), q=n>>3; bn=(q&7)*64, bm=((q>>3)*8+x)*128 —
// the 8 bn-blocks of one A row-panel run consecutively on ONE XCD.
// A = batch_H fp32 -> fp16 fused in staging; bn==0 blocks side-write bHh.
// ---------------------------------------------------------------------------
__global__ __launch_bounds__(256) void gemm_proj(
    const float* __restrict__ A, const u16* __restrict__ Bh,
    u16* __restrict__ bHh, u16* __restrict__ projh)
{
  extern __shared__ char smem[];
  constexpr int STR = 40;
  short* As = (short*)smem;                  // [128][STR]
  short* Bs = As + 128*STR;                  // [64][STR]
  const int tid=threadIdx.x;
  const int n = blockIdx.x;
  const int x = n & 7, q = n >> 3;
  const int bn = (q & 7) * 64;
  const int bm = ((q >> 3)*8 + x) * 128;
  const int w=tid>>6, lane=tid&63, wr=w>>1, wc=w&1;   // WM=64, WN=32
  const bool wrA = ((q & 7) == 0);

  f32x4v acc[4][2];
#pragma unroll
  for (int i=0;i<4;i++)
#pragma unroll
    for (int j=0;j<2;j++) acc[i][j] = (f32x4v){0.f,0.f,0.f,0.f};

  float4 fa[2][2];
  u16x8 rb;
  auto load = [&](int it){
    const int kk = it<<5;
#pragma unroll
    for (int L=0; L<2; L++){
      int t=L*256+tid, row=t>>2, c=(t&3)*8;
      const float* p = &A[(size_t)(bm+row)*512 + kk + c];
      fa[L][0] = *(const float4*)p;
      fa[L][1] = *(const float4*)(p+4);
    }
    { int row=tid>>2, c=(tid&3)*8;
      rb = *(const u16x8*)&Bh[(size_t)(bn+row)*512 + kk + c]; }
  };
  load(0);

  for (int it=0; it<16; ++it){
    const int kk = it<<5;
    __syncthreads();
#pragma unroll
    for (int L=0; L<2; L++){
      int t=L*256+tid, row=t>>2, c=(t&3)*8;
      u16x8 hv;
      hv[0]=f2h_u(fa[L][0].x); hv[1]=f2h_u(fa[L][0].y);
      hv[2]=f2h_u(fa[L][0].z); hv[3]=f2h_u(fa[L][0].w);
      hv[4]=f2h_u(fa[L][1].x); hv[5]=f2h_u(fa[L][1].y);
      hv[6]=f2h_u(fa[L][1].z); hv[7]=f2h_u(fa[L][1].w);
      *(u16x8*)&As[row*STR+c] = hv;
      if (wrA) *(u16x8*)&bHh[(size_t)(bm+row)*512 + kk + c] = hv;
    }
    { int row=tid>>2, c=(tid&3)*8; *(u16x8*)&Bs[row*STR+c] = rb; }
    if (it+1 < 16) load(it+1);
    __syncthreads();
    const int koff = (lane>>4)*8, mrow = lane&15;
#pragma unroll
    for (int i=0;i<4;i++)
#pragma unroll
      for (int j=0;j<2;j++){
        f16x8v af = *(const f16x8v*)&As[(wr*64+i*16+mrow)*STR + koff];
        f16x8v bf = *(const f16x8v*)&Bs[(wc*32+j*16+mrow)*STR + koff];
        acc[i][j] = __builtin_amdgcn_mfma_f32_16x16x32_f16(af, bf, acc[i][j], 0,0,0);
      }
  }

  // epilogue: fp16 out via LDS bounce
  const int r0 = (lane>>4)*4, cn = lane&15;
  __syncthreads();
  u16* Ts = (u16*)smem;   // [128][64]
#pragma unroll
  for (int i=0;i<4;i++)
#pragma unroll
    for (int j=0;j<2;j++)
#pragma unroll
      for (int r=0;r<4;r++)
        Ts[(wr*64+i*16+r0+r)*64 + wc*32+j*16+cn] = f2h_u(acc[i][j][r]);
  __syncthreads();
#pragma unroll
  for (int q2=0;q2<4;q2++){
    int idx = q2*256 + tid;
    int row = idx>>3, c8 = (idx&7)*8;
    *(float4*)&projh[(size_t)(bm+row)*512 + bn + c8] = *(const float4*)&Ts[row*64 + c8];
  }
}

// ---------------------------------------------------------------------------
// bf16 MFMA GEMM (hcombo and generator), K = kSteps*32, NT, bf16x2 3-pass.
// MODE 0: fp32 out + col-bias.  MODE 2: generator out (m->(s,b), n<38, +bias2).
// ---------------------------------------------------------------------------
template<int BM,int BN,int MODE>
__global__ __launch_bounds__(256) void gemm_bf(
    const u16* __restrict__ Ah, const u16* __restrict__ Al, int lda,
    const u16* __restrict__ Bh, const u16* __restrict__ Bl, int ldb,
    float* __restrict__ Cout, int ldc,
    const float* __restrict__ bias2, int npass, int kSteps)
{
  extern __shared__ char smem[];
  constexpr int STR = 40;
  short* As = (short*)smem;                  // [BM][STR]
  short* Bs = As + BM*STR;                   // [BN][STR]
  const int tid=threadIdx.x, bm=blockIdx.y*BM, bn=blockIdx.x*BN;
  const int w=tid>>6, lane=tid&63, wr=w>>1, wc=w&1;
  constexpr int WM=BM/2, WN=BN/2, FM=WM/16, FN=WN/16;
  constexpr int LA=BM/64, LB=BN/64;
  const int nIter = npass*kSteps;

  f32x4v acc[FM][FN];
#pragma unroll
  for (int i=0;i<FM;i++)
#pragma unroll
    for (int j=0;j<FN;j++) acc[i][j] = (f32x4v){0.f,0.f,0.f,0.f};

  u16x8 ra[LA], rb[LB];
  auto load = [&](int it){
    const int pass = it/kSteps, kk = (it%kSteps)<<5;
    const u16* Ap = (pass==2)?Al:Ah;
    const u16* Bp = (pass==1)?Bl:Bh;
#pragma unroll
    for (int L=0; L<LA; L++){
      int t=L*256+tid, row=t>>2, c=(t&3)*8;
      ra[L] = *(const u16x8*)&Ap[(size_t)(bm+row)*lda + kk + c];
    }
#pragma unroll
    for (int L=0; L<LB; L++){
      int t=L*256+tid, row=t>>2, c=(t&3)*8;
      rb[L] = *(const u16x8*)&Bp[(size_t)(bn+row)*ldb + kk + c];
    }
  };
  load(0);

  for (int it=0; it<nIter; ++it){
    __syncthreads();
#pragma unroll
    for (int L=0; L<LA; L++){ int t=L*256+tid; *(u16x8*)&As[(t>>2)*STR+(t&3)*8] = ra[L]; }
#pragma unroll
    for (int L=0; L<LB; L++){ int t=L*256+tid; *(u16x8*)&Bs[(t>>2)*STR+(t&3)*8] = rb[L]; }
    if (it+1 < nIter) load(it+1);
    __syncthreads();
    const int koff = (lane>>4)*8, mrow = lane&15;
#pragma unroll
    for (int i=0;i<FM;i++)
#pragma unroll
      for (int j=0;j<FN;j++){
        bf16x8v af = *(const bf16x8v*)&As[(wr*WM+i*16+mrow)*STR + koff];
        bf16x8v bf = *(const bf16x8v*)&Bs[(wc*WN+j*16+mrow)*STR + koff];
        acc[i][j] = __builtin_amdgcn_mfma_f32_16x16x32_bf16(af, bf, acc[i][j], 0,0,0);
      }
  }

  const int r0 = (lane>>4)*4, cn = lane&15;
  if constexpr (MODE==2){
#pragma unroll
    for (int i=0;i<FM;i++)
#pragma unroll
      for (int j=0;j<FN;j++)
#pragma unroll
        for (int r=0;r<4;r++){
          int m = bm + wr*WM + i*16 + r0 + r;       // m = s*512 + b
          int n2 = bn + wc*WN + j*16 + cn;
          if (n2 < MID_){
            int s = m >> 9, b = m & 511;
            Cout[((size_t)b*S_ + s)*MID_ + n2] = acc[i][j][r] + bias2[n2];
          }
        }
  } else {
#pragma unroll
    for (int i=0;i<FM;i++)
#pragma unroll
      for (int j=0;j<FN;j++)
#pragma unroll
        for (int r=0;r<4;r++){
          int row = bm + wr*WM + i*16 + r0 + r;
          int col = bn + wc*WN + j*16 + cn;
          float v = acc[i][j][r];
          if (bias2) v += bias2[col];
          Cout[(size_t)row*ldc + col] = v;
        }
  }
}

// ---------------------------------------------------------------------------
// Fused attention, 1024 threads (16 waves):
//   pp from combo[b][0:512] (fp32, ld 2560)
//   e[t] = sum_h Ws[h]*fast_tanh(projh[b,t,h]+pp[h]); softmax over t;
//   ctx[b,d] = sum_t alpha[t]*bHh[b,t,d] -> ctx hi/lo planes.
// ---------------------------------------------------------------------------
__global__ __launch_bounds__(1024) void attn_kernel(
    const u16* __restrict__ projh, const float* __restrict__ combo,
    const float* __restrict__ Wscore, const u16* __restrict__ bHh,
    u16* __restrict__ ctx_hi, u16* __restrict__ ctx_lo)
{
  __shared__ float s_e[T_];
  __shared__ float s_red[32];
  __shared__ float s_part[16][D_];
  const int tid=threadIdx.x, b=blockIdx.x, wave=tid>>6, lane=tid&63;

  float pv[8], wv[8];
  {
    const float* pprow = combo + (size_t)b*2560;
    float4 p0=*(const float4*)&pprow[lane*8], p1=*(const float4*)&pprow[lane*8+4];
    float4 w0=*(const float4*)&Wscore[lane*8], w1=*(const float4*)&Wscore[lane*8+4];
    pv[0]=p0.x;pv[1]=p0.y;pv[2]=p0.z;pv[3]=p0.w;pv[4]=p1.x;pv[5]=p1.y;pv[6]=p1.z;pv[7]=p1.w;
    wv[0]=w0.x;wv[1]=w0.y;wv[2]=w0.z;wv[3]=w0.w;wv[4]=w1.x;wv[5]=w1.y;wv[6]=w1.z;wv[7]=w1.w;
  }
  // e-phase: wave w handles t = w, w+16, ... (8 rows); 2-deep pipeline
  {
    const u16* base = projh + (size_t)b*T_*H_ + lane*8;
    u16x8 cur = *(const u16x8*)(base + (size_t)wave*H_);
    for (int t=wave; t<T_; t+=16){
      u16x8 nxt;
      if (t+16 < T_) nxt = *(const u16x8*)(base + (size_t)(t+16)*H_);
      float acc = 0.f;
#pragma unroll
      for (int j=0;j<8;j++) acc += wv[j]*fast_tanh(h2f_u(cur[j]) + pv[j]);
#pragma unroll
      for (int o=32;o>0;o>>=1) acc += __shfl_down(acc,o);
      if (lane==0) s_e[t] = acc;
      cur = nxt;
    }
  }
  __syncthreads();
  // softmax over s_e[0..127]
  float v = (tid < T_) ? s_e[tid] : -INFINITY;
  float m = v;
#pragma unroll
  for (int o=32;o>0;o>>=1) m = fmaxf(m, __shfl_down(m,o));
  if (tid < T_ && lane==0) s_red[wave] = m;      // waves 0,1 write
  __syncthreads();
  m = fmaxf(s_red[0], s_red[1]);
  float p = (tid < T_) ? __expf(v - m) : 0.f;
  float sum = p;
#pragma unroll
  for (int o=32;o>0;o>>=1) sum += __shfl_down(sum,o);
  if (tid < T_ && lane==0) s_red[16+wave] = sum;
  __syncthreads();
  float denom = s_red[16] + s_red[17];
  if (tid < T_) s_e[tid] = p/denom;
  __syncthreads();

  // context: wave w covers t in [8w, 8w+8); lane covers d = lane*8..+7
  const int d0 = lane*8;
  float a[8] = {0,0,0,0,0,0,0,0};
  {
    const u16* base = bHh + (size_t)b*T_*D_ + d0;
    u16x8 cur = *(const u16x8*)(base + (size_t)(wave*8)*D_);
    for (int t=wave*8; t<wave*8+8; ++t){
      u16x8 nxt;
      if (t+1 < wave*8+8) nxt = *(const u16x8*)(base + (size_t)(t+1)*D_);
      const float al = s_e[t];
#pragma unroll
      for (int j=0;j<8;j++) a[j] += al*h2f_u(cur[j]);
      cur = nxt;
    }
  }
  *(float4*)&s_part[wave][d0]   = make_float4(a[0],a[1],a[2],a[3]);
  *(float4*)&s_part[wave][d0+4] = make_float4(a[4],a[5],a[6],a[7]);
  __syncthreads();
  if (tid < D_){
    float vv = s_part[0][tid];
#pragma unroll
    for (int q=1;q<16;q++) vv += s_part[q][tid];
    u16 hh=f2bf_rn(vv), ll=f2bf_rn(vv-bf2f(hh));
    ctx_hi[(size_t)b*512 + tid] = hh;
    ctx_lo[(size_t)b*512 + tid] = ll;
  }
}

// ---------------------------------------------------------------------------
// Fused gates GEMM + LSTM pointwise.  K=512 bf16x2 3-pass, BK=64.
// gates = ctx @ W_ih[:,:512]^T + combo[:,512:] (h-part precomputed).
// A (ctx planes) direct-from-global; B via LDS.  B row n = f*16+jj ->
// Bih row f*512+(j0+jj): fragment f holds gate f.  Epilogue: + combo +
// token adds, activations, c/h update; writes h planes + hid planes.
// ---------------------------------------------------------------------------
__global__ __launch_bounds__(256) void gates_lstm(
    const u16* __restrict__ Ah, const u16* __restrict__ Al,     // [512][512]
    const u16* __restrict__ Bh, const u16* __restrict__ Bl,     // [2048][512]
    const float* __restrict__ combo,                            // [512][2560]
    const float* __restrict__ WmT, const float* __restrict__ WbT,
    const int* __restrict__ midtok, const int* __restrict__ bottok,
    float* __restrict__ c,
    u16* __restrict__ hA_hi, u16* __restrict__ hA_lo,
    u16* __restrict__ hid_hi, u16* __restrict__ hid_lo, int s)
{
  constexpr int STR = 72;
  __shared__ short Bs[64*STR];
  const int tid=threadIdx.x, lane=tid&63, w=tid>>6;
  const int j0 = blockIdx.x*16, bm = blockIdx.y*64;
  const int mrow=lane&15, koff=(lane>>4)*8;
  const int arow = bm + w*16 + mrow;
  const int srow = tid>>2, scc=(tid&3)*8;
  const int sbrow = (srow>>4)*512 + j0 + (srow&15);

  f32x4v acc[4];
#pragma unroll
  for (int f=0;f<4;f++) acc[f] = (f32x4v){0.f,0.f,0.f,0.f};

  u16x8 sb0, sb1;
  bf16x8v a0[2], a1[2];
  auto loadB = [&](int it){
    const int pass = it>>3, kk=(it&7)<<6;
    const u16* Bp = (pass==1)?Bl:Bh;
    sb0 = *(const u16x8*)&Bp[(size_t)sbrow*512 + kk + scc];
    sb1 = *(const u16x8*)&Bp[(size_t)sbrow*512 + kk + scc + 32];
  };
  auto loadA0 = [&](int it){
    const int pass = it>>3, kk=(it&7)<<6;
    const u16* Ap = (pass==2)?Al:Ah;
    a0[0] = *(const bf16x8v*)&Ap[(size_t)arow*512 + kk + koff];
    a0[1] = *(const bf16x8v*)&Ap[(size_t)arow*512 + kk + koff + 32];
  };
  auto loadA1 = [&](int it){
    const int pass = it>>3, kk=(it&7)<<6;
    const u16* Ap = (pass==2)?Al:Ah;
    a1[0] = *(const bf16x8v*)&Ap[(size_t)arow*512 + kk + koff];
    a1[1] = *(const bf16x8v*)&Ap[(size_t)arow*512 + kk + koff + 32];
  };

  loadB(0); loadA0(0);
  for (int it=0; it<24; it+=2){
    __syncthreads();
    *(u16x8*)&Bs[srow*STR+scc]    = sb0;
    *(u16x8*)&Bs[srow*STR+scc+32] = sb1;
    if (it+1 < 24){ loadB(it+1); loadA1(it+1); }
    __syncthreads();
#pragma unroll
    for (int f=0;f<4;f++){
      bf16x8v b0 = *(const bf16x8v*)&Bs[(f*16+mrow)*STR + koff];
      bf16x8v b1 = *(const bf16x8v*)&Bs[(f*16+mrow)*STR + koff + 32];
      acc[f] = __builtin_amdgcn_mfma_f32_16x16x32_bf16(a0[0], b0, acc[f], 0,0,0);
      acc[f] = __builtin_amdgcn_mfma_f32_16x16x32_bf16(a0[1], b1, acc[f], 0,0,0);
    }
    if (it+1 >= 24) break;
    __syncthreads();
    *(u16x8*)&Bs[srow*STR+scc]    = sb0;
    *(u16x8*)&Bs[srow*STR+scc+32] = sb1;
    if (it+2 < 24){ loadB(it+2); loadA0(it+2); }
    __syncthreads();
#pragma unroll
    for (int f=0;f<4;f++){
      bf16x8v b0 = *(const bf16x8v*)&Bs[(f*16+mrow)*STR + koff];
      bf16x8v b1 = *(const bf16x8v*)&Bs[(f*16+mrow)*STR + koff + 32];
      acc[f] = __builtin_amdgcn_mfma_f32_16x16x32_bf16(a1[0], b0, acc[f], 0,0,0);
      acc[f] = __builtin_amdgcn_mfma_f32_16x16x32_bf16(a1[1], b1, acc[f], 0,0,0);
    }
  }

  // epilogue: lane holds gates f=0..3 for rows r0..r0+3 (b), col jj
  const int r0=(lane>>4)*4, jj=lane&15, j=j0+jj;
#pragma unroll
  for (int r=0;r<4;r++){
    const int b = bm + w*16 + r0 + r;
    const int mt = midtok[b*26 + s];
    const int bt = bottok[b*26 + s];
    const float* wm = WmT + (size_t)mt*2048;
    const float* wb = WbT + (size_t)bt*2048;
    const float* cb = combo + (size_t)b*2560 + 512;
    float ig = acc[0][r] + cb[j       ] + wm[j       ] + wb[j       ];
    float fg = acc[1][r] + cb[512 + j ] + wm[512 + j ] + wb[512 + j ];
    float gg = acc[2][r] + cb[1024 + j] + wm[1024 + j] + wb[1024 + j];
    float og = acc[3][r] + cb[1536 + j] + wm[1536 + j] + wb[1536 + j];
    ig = fast_sig(ig);
    fg = fast_sig(fg);
    gg = fast_tanh(gg);
    og = fast_sig(og);
    const size_t ci = (size_t)b*512 + j;
    const float cn = fg*c[ci] + ig*gg;
    const float hn = og*fast_tanh(cn);
    c[ci] = cn;
    u16 hh = f2bf_rn(hn), hl = f2bf_rn(hn - bf2f(hh));
    hA_hi[ci] = hh;
    hA_lo[ci] = hl;
    hid_hi[((size_t)s*512 + b)*512 + j] = hh;
    hid_lo[((size_t)s*512 + b)*512 + j] = hl;
  }
}

extern "C" void kernel_launch(void* const* d_in, const int* in_sizes, int n_in,
                              void* d_out, int out_size, void* d_ws, size_t ws_size,
                              hipStream_t stream) {
  const float* bH   = (const float*)d_in[0];
  const int*   midt = (const int*)  d_in[1];
  const int*   bott = (const int*)  d_in[2];
  const float* Wi2h = (const float*)d_in[3];
  const float* Wh2h = (const float*)d_in[4];
  const float* bh2h = (const float*)d_in[5];
  const float* Wsc  = (const float*)d_in[6];
  const float* Wih  = (const float*)d_in[7];
  const float* Whh  = (const float*)d_in[8];
  const float* bih  = (const float*)d_in[9];
  const float* bhh  = (const float*)d_in[10];
  const float* Wgen = (const float*)d_in[11];
  const float* bgen = (const float*)d_in[12];
  float* out = (float*)d_out;

  char* wp = (char*)d_ws;
  u16* projh   = (u16*)wp; wp += (size_t)B_*T_*H_*2;      // 67.1 MB fp16
  u16* bHh     = (u16*)wp; wp += (size_t)B_*T_*D_*2;      // 67.1 MB fp16
  u16* Bh2_hi  = (u16*)wp; wp += (size_t)2560*512*2;      // [W_h2h|W_hh] planes
  u16* Bh2_lo  = (u16*)wp; wp += (size_t)2560*512*2;
  u16* Bih_hi  = (u16*)wp; wp += (size_t)2048*512*2;      // W_ih[:, :512] planes
  u16* Bih_lo  = (u16*)wp; wp += (size_t)2048*512*2;
  u16* Wi2h_h  = (u16*)wp; wp += (size_t)512*512*2;       // fp16
  u16* Wg_hi   = (u16*)wp; wp += (size_t)64*512*2;
  u16* Wg_lo   = (u16*)wp; wp += (size_t)64*512*2;
  u16* ctx_hi  = (u16*)wp; wp += (size_t)B_*512*2;
  u16* ctx_lo  = (u16*)wp; wp += (size_t)B_*512*2;
  u16* hA_hi   = (u16*)wp; wp += (size_t)B_*512*2;
  u16* hA_lo   = (u16*)wp; wp += (size_t)B_*512*2;
  u16* hid_hi  = (u16*)wp; wp += (size_t)S_*B_*H_*2;      // 13.6 MB
  u16* hid_lo  = (u16*)wp; wp += (size_t)S_*B_*H_*2;
  float* combo = (float*)wp; wp += (size_t)B_*2560*4;     // 5.2 MB
  float* c     = (float*)wp; wp += (size_t)B_*H_*4;
  float* bcombF= (float*)wp; wp += (size_t)2560*4;
  float* WmT   = (float*)wp; wp += (size_t)MID_*2048*4;
  float* WbT   = (float*)wp; wp += (size_t)BOT_*2048*4;
  if ((size_t)(wp - (char*)d_ws) > ws_size) return;  // fail loudly

  hipMemsetAsync(hA_hi, 0, (size_t)B_*512*2, stream);
  hipMemsetAsync(hA_lo, 0, (size_t)B_*512*2, stream);
  hipMemsetAsync(c, 0, (size_t)B_*H_*4, stream);

  setup_all<<<2048, 256, 0, stream>>>(
      Wi2h, Wh2h, Whh, Wih, Wgen, bh2h, bih, bhh,
      Wi2h_h, Bh2_hi, Bh2_lo, Bih_hi, Bih_lo, Wg_hi, Wg_lo,
      WmT, WbT, bcombF);

  // proj = fp16( batch_H @ W_i2h^T ), BN=64, XCD-aware 1D grid
  gemm_proj<<<4096, 256, 16384, stream>>>(bH, Wi2h_h, bHh, projh);

  for (int s=0; s<S_; ++s){
    // combo = h @ [W_h2h | W_hh]^T + [b_h2h | b_ih+b_hh]   (bf16x2, N=2560)
    gemm_bf<64,64,0><<<dim3(40,8), 256, 10240, stream>>>(
        hA_hi, hA_lo, 512, Bh2_hi, Bh2_lo, 512,
        combo, 2560, bcombF, 3, 16);
    attn_kernel<<<B_, 1024, 0, stream>>>(
        projh, combo, Wsc, bHh, ctx_hi, ctx_lo);
    gates_lstm<<<dim3(32,8), 256, 0, stream>>>(
        ctx_hi, ctx_lo, Bih_hi, Bih_lo, combo, WmT, WbT,
        midt, bott, c, hA_hi, hA_lo,
        hid_hi, hid_lo, s);
  }

  // out = hid @ W_gen^T + b_gen  (bf16x2), M = S*B = 13312, N=64 (n<38 kept)
  gemm_bf<64,64,2><<<dim3(1,208), 256, 10240, stream>>>(
      hid_hi, hid_lo, 512, Wg_hi, Wg_lo, 512,
      out, 0, bgen, 3, 16);
}

// Round 11
// 1655.152 us; speedup vs baseline: 1.1612x; 1.0212x over previous
//
#include <hip/hip_runtime.h>
#include <hip/hip_bf16.h>
#include <hip/hip_fp16.h>
#include <cstdint>
#include <cstddef>

#define B_   512
#define T_   128
#define D_   512
#define H_   512
#define MID_ 38
#define BOT_ 38
#define S_   26
#define XL_  588   // D + MID + BOT = W_ih row length

typedef unsigned short u16;
typedef __attribute__((ext_vector_type(8))) short bf16x8v;
typedef __attribute__((ext_vector_type(8))) _Float16 f16x8v;
typedef __attribute__((ext_vector_type(8))) unsigned short u16x8;
typedef __attribute__((ext_vector_type(4))) float f32x4v;

__device__ __forceinline__ u16 f2bf_rn(float f){
  unsigned u = __float_as_uint(f);
  return (u16)((u + 0x7fffu + ((u>>16)&1u)) >> 16);
}
__device__ __forceinline__ float bf2f(u16 v){ return __uint_as_float(((unsigned)v)<<16); }
__device__ __forceinline__ u16 f2h_u(float f){ return __half_as_ushort(__float2half(f)); }
__device__ __forceinline__ float h2f_u(u16 u){ return __half2float(__ushort_as_half(u)); }

// branch-free fast transcendentals (v_exp_f32 + v_rcp_f32, ~1e-6 rel err)
__device__ __forceinline__ float fast_tanh(float x){
  return 1.0f - 2.0f*__builtin_amdgcn_rcpf(__expf(2.0f*x) + 1.0f);
}
__device__ __forceinline__ float fast_sig(float x){
  return __builtin_amdgcn_rcpf(1.0f + __expf(-x));
}

// ---------------------------------------------------------------------------
// One-shot setup: bH->fp16, weight conversions, token tables, bias combine,
// h/c zero-init.  Flat quad-index space, grid-stride.
// ---------------------------------------------------------------------------
__device__ __forceinline__ void cvt_hilo4(const float* src, u16* hi, u16* lo){
  float4 v = *(const float4*)src;
  ushort4 h, l;
  h.x=f2bf_rn(v.x); h.y=f2bf_rn(v.y); h.z=f2bf_rn(v.z); h.w=f2bf_rn(v.w);
  l.x=f2bf_rn(v.x-bf2f(h.x)); l.y=f2bf_rn(v.y-bf2f(h.y));
  l.z=f2bf_rn(v.z-bf2f(h.z)); l.w=f2bf_rn(v.w-bf2f(h.w));
  *(ushort4*)hi = h; *(ushort4*)lo = l;
}

__global__ __launch_bounds__(256) void setup_all(
    const float* __restrict__ bH,
    const float* __restrict__ Wi2h, const float* __restrict__ Wh2h,
    const float* __restrict__ Whh,  const float* __restrict__ Wih,
    const float* __restrict__ Wgen, const float* __restrict__ bh2h,
    const float* __restrict__ bih,  const float* __restrict__ bhh,
    u16* __restrict__ bHh,
    u16* __restrict__ Wi2h_h, u16* __restrict__ Bh2_hi, u16* __restrict__ Bh2_lo,
    u16* __restrict__ Bih_hi, u16* __restrict__ Bih_lo,
    u16* __restrict__ Wg_hi,  u16* __restrict__ Wg_lo,
    float* __restrict__ WmT, float* __restrict__ WbT, float* __restrict__ bcombF,
    u16* __restrict__ hA_hi, u16* __restrict__ hA_lo, float* __restrict__ c)
{
  const int T0 = 8388608;               // bH -> fp16 (65536 rows x 128 quads)
  const int T1 = T0+65536;              // Wi2h -> fp16
  const int T2 = T1+65536;              // Wh2h -> Bh2[0:512] hi/lo
  const int T3 = T2+262144;             // Whh  -> Bh2[512:2560]
  const int T4 = T3+262144;             // Wih[:, :512] -> Bih
  const int T5 = T4+8192;               // Wgen -> Wg (pad 64 rows)
  const int T6 = T5+19456;              // token tables (38*512 quads)
  const int T7 = T6+640;                // bcombF
  const int T8 = T7+65536;              // hA hi/lo zero (ushort4 each)
  const int T9 = T8+65536;              // c zero (float4)
  for (int i = blockIdx.x*256 + threadIdx.x; i < T9; i += gridDim.x*256){
    if (i < T0){
      int row=i>>7, c4=(i&127)*4;
      float4 v = *(const float4*)&bH[(size_t)row*512 + c4];
      ushort4 h; h.x=f2h_u(v.x); h.y=f2h_u(v.y); h.z=f2h_u(v.z); h.w=f2h_u(v.w);
      *(ushort4*)&bHh[(size_t)row*512 + c4] = h;
    } else if (i < T1){
      int j=i-T0, row=j>>7, c4=(j&127)*4;
      float4 v = *(const float4*)&Wi2h[(size_t)row*512 + c4];
      ushort4 h; h.x=f2h_u(v.x); h.y=f2h_u(v.y); h.z=f2h_u(v.z); h.w=f2h_u(v.w);
      *(ushort4*)&Wi2h_h[(size_t)row*512 + c4] = h;
    } else if (i < T2){
      int j=i-T1, row=j>>7, c4=(j&127)*4;
      cvt_hilo4(&Wh2h[(size_t)row*512+c4], &Bh2_hi[(size_t)row*512+c4], &Bh2_lo[(size_t)row*512+c4]);
    } else if (i < T3){
      int j=i-T2, row=j>>7, c4=(j&127)*4;
      cvt_hilo4(&Whh[(size_t)row*512+c4],
                &Bh2_hi[(size_t)(512+row)*512+c4], &Bh2_lo[(size_t)(512+row)*512+c4]);
    } else if (i < T4){
      int j=i-T3, row=j>>7, c4=(j&127)*4;
      cvt_hilo4(&Wih[(size_t)row*XL_+c4], &Bih_hi[(size_t)row*512+c4], &Bih_lo[(size_t)row*512+c4]);
    } else if (i < T5){
      int j=i-T4, row=j>>7, c4=(j&127)*4;
      float4 v = make_float4(0.f,0.f,0.f,0.f);
      if (row < MID_) v = *(const float4*)&Wgen[(size_t)row*512 + c4];
      ushort4 h, l;
      h.x=f2bf_rn(v.x); h.y=f2bf_rn(v.y); h.z=f2bf_rn(v.z); h.w=f2bf_rn(v.w);
      l.x=f2bf_rn(v.x-bf2f(h.x)); l.y=f2bf_rn(v.y-bf2f(h.y));
      l.z=f2bf_rn(v.z-bf2f(h.z)); l.w=f2bf_rn(v.w-bf2f(h.w));
      *(ushort4*)&Wg_hi[(size_t)row*512+c4] = h;
      *(ushort4*)&Wg_lo[(size_t)row*512+c4] = l;
    } else if (i < T6){
      int j=i-T5;                    // 38*512
      int cc=j>>9, jq=j&511;
#pragma unroll
      for (int u=0;u<4;u++){
        int jj=jq*4+u;
        WmT[(size_t)cc*2048+jj] = Wih[(size_t)jj*XL_ + 512 + cc];
        WbT[(size_t)cc*2048+jj] = Wih[(size_t)jj*XL_ + 512 + MID_ + cc];
      }
    } else if (i < T7){
      int j=(i-T6)*4;
#pragma unroll
      for (int u=0;u<4;u++){
        int k=j+u;
        if (k < 512) bcombF[k] = bh2h[k];
        else if (k < 2560) bcombF[k] = bih[k-512] + bhh[k-512];
      }
    } else if (i < T8){
      int j=i-T7;
      ushort4 z = {0,0,0,0};
      *(ushort4*)&hA_hi[(size_t)j*4] = z;
      *(ushort4*)&hA_lo[(size_t)j*4] = z;
    } else {
      int j=i-T8;
      *(float4*)&c[(size_t)j*4] = make_float4(0.f,0.f,0.f,0.f);
    }
  }
}

// ---------------------------------------------------------------------------
// proj GEMM, pure fp16, BM=BN=128, XCD-aware 1D grid (2048 blocks):
// x=n&7 (XCD), q=n>>3; bn=(q&3)*128, bm=((q>>2)*8+x)*128 — the 4 bn-blocks
// of one A row-panel run consecutively on ONE XCD (A L2-reused).
// A = bHh fp16 (pre-converted), B = Wi2h fp16.  C = fp16 projh via LDS bounce.
// ---------------------------------------------------------------------------
__global__ __launch_bounds__(256) void gemm_proj16(
    const u16* __restrict__ Ah, const u16* __restrict__ Bh,
    u16* __restrict__ projh)
{
  extern __shared__ char smem[];
  constexpr int STR = 40;
  short* As = (short*)smem;                  // [128][STR]
  short* Bs = As + 128*STR;
  const int tid=threadIdx.x;
  const int n = blockIdx.x;
  const int x = n & 7, q = n >> 3;
  const int bn = (q & 3) * 128;
  const int bm = ((q >> 2)*8 + x) * 128;
  const int w=tid>>6, lane=tid&63, wr=w>>1, wc=w&1;

  f32x4v acc[4][4];
#pragma unroll
  for (int i=0;i<4;i++)
#pragma unroll
    for (int j=0;j<4;j++) acc[i][j] = (f32x4v){0.f,0.f,0.f,0.f};

  u16x8 ra[2], rb[2];
  auto load = [&](int it){
    const int kk = it<<5;
#pragma unroll
    for (int L=0; L<2; L++){
      int t=L*256+tid, row=t>>2, c=(t&3)*8;
      ra[L] = *(const u16x8*)&Ah[(size_t)(bm+row)*512 + kk + c];
      rb[L] = *(const u16x8*)&Bh[(size_t)(bn+row)*512 + kk + c];
    }
  };
  load(0);

  for (int it=0; it<16; ++it){
    __syncthreads();
#pragma unroll
    for (int L=0; L<2; L++){
      int t=L*256+tid, row=t>>2, c=(t&3)*8;
      *(u16x8*)&As[row*STR+c] = ra[L];
      *(u16x8*)&Bs[row*STR+c] = rb[L];
    }
    if (it+1 < 16) load(it+1);
    __syncthreads();
    const int koff = (lane>>4)*8, mrow = lane&15;
#pragma unroll
    for (int i=0;i<4;i++)
#pragma unroll
      for (int j=0;j<4;j++){
        f16x8v af = *(const f16x8v*)&As[(wr*64+i*16+mrow)*STR + koff];
        f16x8v bf = *(const f16x8v*)&Bs[(wc*64+j*16+mrow)*STR + koff];
        acc[i][j] = __builtin_amdgcn_mfma_f32_16x16x32_f16(af, bf, acc[i][j], 0,0,0);
      }
  }

  // epilogue: fp16 out via LDS bounce
  const int r0 = (lane>>4)*4, cn = lane&15;
  __syncthreads();
  u16* Ts = (u16*)smem;   // [128][128]
#pragma unroll
  for (int i=0;i<4;i++)
#pragma unroll
    for (int j=0;j<4;j++)
#pragma unroll
      for (int r=0;r<4;r++)
        Ts[(wr*64+i*16+r0+r)*128 + wc*64+j*16+cn] = f2h_u(acc[i][j][r]);
  __syncthreads();
#pragma unroll
  for (int q2=0;q2<8;q2++){
    int idx = q2*256 + tid;
    int row = idx>>4, c8 = (idx&15)*8;
    *(float4*)&projh[(size_t)(bm+row)*512 + bn + c8] = *(const float4*)&Ts[row*128 + c8];
  }
}

// ---------------------------------------------------------------------------
// bf16 MFMA GEMM (hcombo and generator), K = kSteps*32, NT, bf16x2 3-pass.
// MODE 0: fp32 out + col-bias.  MODE 2: generator out (m->(s,b), n<38, +bias2).
// ---------------------------------------------------------------------------
template<int BM,int BN,int MODE>
__global__ __launch_bounds__(256) void gemm_bf(
    const u16* __restrict__ Ah, const u16* __restrict__ Al, int lda,
    const u16* __restrict__ Bh, const u16* __restrict__ Bl, int ldb,
    float* __restrict__ Cout, int ldc,
    const float* __restrict__ bias2, int npass, int kSteps)
{
  extern __shared__ char smem[];
  constexpr int STR = 40;
  short* As = (short*)smem;                  // [BM][STR]
  short* Bs = As + BM*STR;                   // [BN][STR]
  const int tid=threadIdx.x, bm=blockIdx.y*BM, bn=blockIdx.x*BN;
  const int w=tid>>6, lane=tid&63, wr=w>>1, wc=w&1;
  constexpr int WM=BM/2, WN=BN/2, FM=WM/16, FN=WN/16;
  constexpr int LA=BM/64, LB=BN/64;
  const int nIter = npass*kSteps;

  f32x4v acc[FM][FN];
#pragma unroll
  for (int i=0;i<FM;i++)
#pragma unroll
    for (int j=0;j<FN;j++) acc[i][j] = (f32x4v){0.f,0.f,0.f,0.f};

  u16x8 ra[LA], rb[LB];
  auto load = [&](int it){
    const int pass = it/kSteps, kk = (it%kSteps)<<5;
    const u16* Ap = (pass==2)?Al:Ah;
    const u16* Bp = (pass==1)?Bl:Bh;
#pragma unroll
    for (int L=0; L<LA; L++){
      int t=L*256+tid, row=t>>2, c=(t&3)*8;
      ra[L] = *(const u16x8*)&Ap[(size_t)(bm+row)*lda + kk + c];
    }
#pragma unroll
    for (int L=0; L<LB; L++){
      int t=L*256+tid, row=t>>2, c=(t&3)*8;
      rb[L] = *(const u16x8*)&Bp[(size_t)(bn+row)*ldb + kk + c];
    }
  };
  load(0);

  for (int it=0; it<nIter; ++it){
    __syncthreads();
#pragma unroll
    for (int L=0; L<LA; L++){ int t=L*256+tid; *(u16x8*)&As[(t>>2)*STR+(t&3)*8] = ra[L]; }
#pragma unroll
    for (int L=0; L<LB; L++){ int t=L*256+tid; *(u16x8*)&Bs[(t>>2)*STR+(t&3)*8] = rb[L]; }
    if (it+1 < nIter) load(it+1);
    __syncthreads();
    const int koff = (lane>>4)*8, mrow = lane&15;
#pragma unroll
    for (int i=0;i<FM;i++)
#pragma unroll
      for (int j=0;j<FN;j++){
        bf16x8v af = *(const bf16x8v*)&As[(wr*WM+i*16+mrow)*STR + koff];
        bf16x8v bf = *(const bf16x8v*)&Bs[(wc*WN+j*16+mrow)*STR + koff];
        acc[i][j] = __builtin_amdgcn_mfma_f32_16x16x32_bf16(af, bf, acc[i][j], 0,0,0);
      }
  }

  const int r0 = (lane>>4)*4, cn = lane&15;
  if constexpr (MODE==2){
#pragma unroll
    for (int i=0;i<FM;i++)
#pragma unroll
      for (int j=0;j<FN;j++)
#pragma unroll
        for (int r=0;r<4;r++){
          int m = bm + wr*WM + i*16 + r0 + r;       // m = s*512 + b
          int n2 = bn + wc*WN + j*16 + cn;
          if (n2 < MID_){
            int s = m >> 9, b = m & 511;
            Cout[((size_t)b*S_ + s)*MID_ + n2] = acc[i][j][r] + bias2[n2];
          }
        }
  } else {
#pragma unroll
    for (int i=0;i<FM;i++)
#pragma unroll
      for (int j=0;j<FN;j++)
#pragma unroll
        for (int r=0;r<4;r++){
          int row = bm + wr*WM + i*16 + r0 + r;
          int col = bn + wc*WN + j*16 + cn;
          float v = acc[i][j][r];
          if (bias2) v += bias2[col];
          Cout[(size_t)row*ldc + col] = v;
        }
  }
}

// ---------------------------------------------------------------------------
// Fused attention, 1024 threads (16 waves):
//   pp from combo[b][0:512] (fp32, ld 2560)
//   e[t] = sum_h Ws[h]*fast_tanh(projh[b,t,h]+pp[h]); softmax over t;
//   ctx[b,d] = sum_t alpha[t]*bHh[b,t,d] -> ctx hi/lo planes.
// ---------------------------------------------------------------------------
__global__ __launch_bounds__(1024) void attn_kernel(
    const u16* __restrict__ projh, const float* __restrict__ combo,
    const float* __restrict__ Wscore, const u16* __restrict__ bHh,
    u16* __restrict__ ctx_hi, u16* __restrict__ ctx_lo)
{
  __shared__ float s_e[T_];
  __shared__ float s_red[32];
  __shared__ float s_part[16][D_];
  const int tid=threadIdx.x, b=blockIdx.x, wave=tid>>6, lane=tid&63;

  float pv[8], wv[8];
  {
    const float* pprow = combo + (size_t)b*2560;
    float4 p0=*(const float4*)&pprow[lane*8], p1=*(const float4*)&pprow[lane*8+4];
    float4 w0=*(const float4*)&Wscore[lane*8], w1=*(const float4*)&Wscore[lane*8+4];
    pv[0]=p0.x;pv[1]=p0.y;pv[2]=p0.z;pv[3]=p0.w;pv[4]=p1.x;pv[5]=p1.y;pv[6]=p1.z;pv[7]=p1.w;
    wv[0]=w0.x;wv[1]=w0.y;wv[2]=w0.z;wv[3]=w0.w;wv[4]=w1.x;wv[5]=w1.y;wv[6]=w1.z;wv[7]=w1.w;
  }
  // e-phase: wave w handles t = w, w+16, ... (8 rows); 2-deep pipeline
  {
    const u16* base = projh + (size_t)b*T_*H_ + lane*8;
    u16x8 cur = *(const u16x8*)(base + (size_t)wave*H_);
    for (int t=wave; t<T_; t+=16){
      u16x8 nxt;
      if (t+16 < T_) nxt = *(const u16x8*)(base + (size_t)(t+16)*H_);
      float acc = 0.f;
#pragma unroll
      for (int j=0;j<8;j++) acc += wv[j]*fast_tanh(h2f_u(cur[j]) + pv[j]);
#pragma unroll
      for (int o=32;o>0;o>>=1) acc += __shfl_down(acc,o);
      if (lane==0) s_e[t] = acc;
      cur = nxt;
    }
  }
  __syncthreads();
  // softmax over s_e[0..127]
  float v = (tid < T_) ? s_e[tid] : -INFINITY;
  float m = v;
#pragma unroll
  for (int o=32;o>0;o>>=1) m = fmaxf(m, __shfl_down(m,o));
  if (tid < T_ && lane==0) s_red[wave] = m;      // waves 0,1 write
  __syncthreads();
  m = fmaxf(s_red[0], s_red[1]);
  float p = (tid < T_) ? __expf(v - m) : 0.f;
  float sum = p;
#pragma unroll
  for (int o=32;o>0;o>>=1) sum += __shfl_down(sum,o);
  if (tid < T_ && lane==0) s_red[16+wave] = sum;
  __syncthreads();
  float denom = s_red[16] + s_red[17];
  if (tid < T_) s_e[tid] = p/denom;
  __syncthreads();

  // context: wave w covers t in [8w, 8w+8); lane covers d = lane*8..+7
  const int d0 = lane*8;
  float a[8] = {0,0,0,0,0,0,0,0};
  {
    const u16* base = bHh + (size_t)b*T_*D_ + d0;
    u16x8 cur = *(const u16x8*)(base + (size_t)(wave*8)*D_);
    for (int t=wave*8; t<wave*8+8; ++t){
      u16x8 nxt;
      if (t+1 < wave*8+8) nxt = *(const u16x8*)(base + (size_t)(t+1)*D_);
      const float al = s_e[t];
#pragma unroll
      for (int j=0;j<8;j++) a[j] += al*h2f_u(cur[j]);
      cur = nxt;
    }
  }
  *(float4*)&s_part[wave][d0]   = make_float4(a[0],a[1],a[2],a[3]);
  *(float4*)&s_part[wave][d0+4] = make_float4(a[4],a[5],a[6],a[7]);
  __syncthreads();
  if (tid < D_){
    float vv = s_part[0][tid];
#pragma unroll
    for (int q=1;q<16;q++) vv += s_part[q][tid];
    u16 hh=f2bf_rn(vv), ll=f2bf_rn(vv-bf2f(hh));
    ctx_hi[(size_t)b*512 + tid] = hh;
    ctx_lo[(size_t)b*512 + tid] = ll;
  }
}

// ---------------------------------------------------------------------------
// Fused gates GEMM + LSTM pointwise.  K=512 bf16x2 3-pass, BK=64.
// gates = ctx @ W_ih[:,:512]^T + combo[:,512:] (h-part precomputed).
// A (ctx planes) direct-from-global; B via LDS.  B row n = f*16+jj ->
// Bih row f*512+(j0+jj): fragment f holds gate f.  Epilogue: + combo +
// token adds, activations, c/h update; writes h planes + hid planes.
// ---------------------------------------------------------------------------
__global__ __launch_bounds__(256) void gates_lstm(
    const u16* __restrict__ Ah, const u16* __restrict__ Al,     // [512][512]
    const u16* __restrict__ Bh, const u16* __restrict__ Bl,     // [2048][512]
    const float* __restrict__ combo,                            // [512][2560]
    const float* __restrict__ WmT, const float* __restrict__ WbT,
    const int* __restrict__ midtok, const int* __restrict__ bottok,
    float* __restrict__ c,
    u16* __restrict__ hA_hi, u16* __restrict__ hA_lo,
    u16* __restrict__ hid_hi, u16* __restrict__ hid_lo, int s)
{
  constexpr int STR = 72;
  __shared__ short Bs[64*STR];
  const int tid=threadIdx.x, lane=tid&63, w=tid>>6;
  const int j0 = blockIdx.x*16, bm = blockIdx.y*64;
  const int mrow=lane&15, koff=(lane>>4)*8;
  const int arow = bm + w*16 + mrow;
  const int srow = tid>>2, scc=(tid&3)*8;
  const int sbrow = (srow>>4)*512 + j0 + (srow&15);

  f32x4v acc[4];
#pragma unroll
  for (int f=0;f<4;f++) acc[f] = (f32x4v){0.f,0.f,0.f,0.f};

  u16x8 sb0, sb1;
  bf16x8v a0[2], a1[2];
  auto loadB = [&](int it){
    const int pass = it>>3, kk=(it&7)<<6;
    const u16* Bp = (pass==1)?Bl:Bh;
    sb0 = *(const u16x8*)&Bp[(size_t)sbrow*512 + kk + scc];
    sb1 = *(const u16x8*)&Bp[(size_t)sbrow*512 + kk + scc + 32];
  };
  auto loadA0 = [&](int it){
    const int pass = it>>3, kk=(it&7)<<6;
    const u16* Ap = (pass==2)?Al:Ah;
    a0[0] = *(const bf16x8v*)&Ap[(size_t)arow*512 + kk + koff];
    a0[1] = *(const bf16x8v*)&Ap[(size_t)arow*512 + kk + koff + 32];
  };
  auto loadA1 = [&](int it){
    const int pass = it>>3, kk=(it&7)<<6;
    const u16* Ap = (pass==2)?Al:Ah;
    a1[0] = *(const bf16x8v*)&Ap[(size_t)arow*512 + kk + koff];
    a1[1] = *(const bf16x8v*)&Ap[(size_t)arow*512 + kk + koff + 32];
  };

  loadB(0); loadA0(0);
  for (int it=0; it<24; it+=2){
    __syncthreads();
    *(u16x8*)&Bs[srow*STR+scc]    = sb0;
    *(u16x8*)&Bs[srow*STR+scc+32] = sb1;
    if (it+1 < 24){ loadB(it+1); loadA1(it+1); }
    __syncthreads();
#pragma unroll
    for (int f=0;f<4;f++){
      bf16x8v b0 = *(const bf16x8v*)&Bs[(f*16+mrow)*STR + koff];
      bf16x8v b1 = *(const bf16x8v*)&Bs[(f*16+mrow)*STR + koff + 32];
      acc[f] = __builtin_amdgcn_mfma_f32_16x16x32_bf16(a0[0], b0, acc[f], 0,0,0);
      acc[f] = __builtin_amdgcn_mfma_f32_16x16x32_bf16(a0[1], b1, acc[f], 0,0,0);
    }
    if (it+1 >= 24) break;
    __syncthreads();
    *(u16x8*)&Bs[srow*STR+scc]    = sb0;
    *(u16x8*)&Bs[srow*STR+scc+32] = sb1;
    if (it+2 < 24){ loadB(it+2); loadA0(it+2); }
    __syncthreads();
#pragma unroll
    for (int f=0;f<4;f++){
      bf16x8v b0 = *(const bf16x8v*)&Bs[(f*16+mrow)*STR + koff];
      bf16x8v b1 = *(const bf16x8v*)&Bs[(f*16+mrow)*STR + koff + 32];
      acc[f] = __builtin_amdgcn_mfma_f32_16x16x32_bf16(a1[0], b0, acc[f], 0,0,0);
      acc[f] = __builtin_amdgcn_mfma_f32_16x16x32_bf16(a1[1], b1, acc[f], 0,0,0);
    }
  }

  // epilogue: lane holds gates f=0..3 for rows r0..r0+3 (b), col jj
  const int r0=(lane>>4)*4, jj=lane&15, j=j0+jj;
#pragma unroll
  for (int r=0;r<4;r++){
    const int b = bm + w*16 + r0 + r;
    const int mt = midtok[b*26 + s];
    const int bt = bottok[b*26 + s];
    const float* wm = WmT + (size_t)mt*2048;
    const float* wb = WbT + (size_t)bt*2048;
    const float* cb = combo + (size_t)b*2560 + 512;
    float ig = acc[0][r] + cb[j       ] + wm[j       ] + wb[j       ];
    float fg = acc[1][r] + cb[512 + j ] + wm[512 + j ] + wb[512 + j ];
    float gg = acc[2][r] + cb[1024 + j] + wm[1024 + j] + wb[1024 + j];
    float og = acc[3][r] + cb[1536 + j] + wm[1536 + j] + wb[1536 + j];
    ig = fast_sig(ig);
    fg = fast_sig(fg);
    gg = fast_tanh(gg);
    og = fast_sig(og);
    const size_t ci = (size_t)b*512 + j;
    const float cn = fg*c[ci] + ig*gg;
    const float hn = og*fast_tanh(cn);
    c[ci] = cn;
    u16 hh = f2bf_rn(hn), hl = f2bf_rn(hn - bf2f(hh));
    hA_hi[ci] = hh;
    hA_lo[ci] = hl;
    hid_hi[((size_t)s*512 + b)*512 + j] = hh;
    hid_lo[((size_t)s*512 + b)*512 + j] = hl;
  }
}

extern "C" void kernel_launch(void* const* d_in, const int* in_sizes, int n_in,
                              void* d_out, int out_size, void* d_ws, size_t ws_size,
                              hipStream_t stream) {
  const float* bH   = (const float*)d_in[0];
  const int*   midt = (const int*)  d_in[1];
  const int*   bott = (const int*)  d_in[2];
  const float* Wi2h = (const float*)d_in[3];
  const float* Wh2h = (const float*)d_in[4];
  const float* bh2h = (const float*)d_in[5];
  const float* Wsc  = (const float*)d_in[6];
  const float* Wih  = (const float*)d_in[7];
  const float* Whh  = (const float*)d_in[8];
  const float* bih  = (const float*)d_in[9];
  const float* bhh  = (const float*)d_in[10];
  const float* Wgen = (const float*)d_in[11];
  const float* bgen = (const float*)d_in[12];
  float* out = (float*)d_out;

  char* wp = (char*)d_ws;
  u16* projh   = (u16*)wp; wp += (size_t)B_*T_*H_*2;      // 67.1 MB fp16
  u16* bHh     = (u16*)wp; wp += (size_t)B_*T_*D_*2;      // 67.1 MB fp16
  u16* Bh2_hi  = (u16*)wp; wp += (size_t)2560*512*2;      // [W_h2h|W_hh] planes
  u16* Bh2_lo  = (u16*)wp; wp += (size_t)2560*512*2;
  u16* Bih_hi  = (u16*)wp; wp += (size_t)2048*512*2;      // W_ih[:, :512] planes
  u16* Bih_lo  = (u16*)wp; wp += (size_t)2048*512*2;
  u16* Wi2h_h  = (u16*)wp; wp += (size_t)512*512*2;       // fp16
  u16* Wg_hi   = (u16*)wp; wp += (size_t)64*512*2;
  u16* Wg_lo   = (u16*)wp; wp += (size_t)64*512*2;
  u16* ctx_hi  = (u16*)wp; wp += (size_t)B_*512*2;
  u16* ctx_lo  = (u16*)wp; wp += (size_t)B_*512*2;
  u16* hA_hi   = (u16*)wp; wp += (size_t)B_*512*2;
  u16* hA_lo   = (u16*)wp; wp += (size_t)B_*512*2;
  u16* hid_hi  = (u16*)wp; wp += (size_t)S_*B_*H_*2;      // 13.6 MB
  u16* hid_lo  = (u16*)wp; wp += (size_t)S_*B_*H_*2;
  float* combo = (float*)wp; wp += (size_t)B_*2560*4;     // 5.2 MB
  float* c     = (float*)wp; wp += (size_t)B_*H_*4;
  float* bcombF= (float*)wp; wp += (size_t)2560*4;
  float* WmT   = (float*)wp; wp += (size_t)MID_*2048*4;
  float* WbT   = (float*)wp; wp += (size_t)BOT_*2048*4;
  if ((size_t)(wp - (char*)d_ws) > ws_size) return;  // fail loudly

  setup_all<<<4096, 256, 0, stream>>>(
      bH, Wi2h, Wh2h, Whh, Wih, Wgen, bh2h, bih, bhh,
      bHh, Wi2h_h, Bh2_hi, Bh2_lo, Bih_hi, Bih_lo, Wg_hi, Wg_lo,
      WmT, WbT, bcombF, hA_hi, hA_lo, c);

  // proj = fp16( bHh @ Wi2h^T ), pure fp16, XCD-aware 1D grid
  gemm_proj16<<<2048, 256, 32768, stream>>>(bHh, Wi2h_h, projh);

  for (int s=0; s<S_; ++s){
    // combo = h @ [W_h2h | W_hh]^T + [b_h2h | b_ih+b_hh]   (bf16x2, N=2560)
    gemm_bf<64,64,0><<<dim3(40,8), 256, 10240, stream>>>(
        hA_hi, hA_lo, 512, Bh2_hi, Bh2_lo, 512,
        combo, 2560, bcombF, 3, 16);
    attn_kernel<<<B_, 1024, 0, stream>>>(
        projh, combo, Wsc, bHh, ctx_hi, ctx_lo);
    gates_lstm<<<dim3(32,8), 256, 0, stream>>>(
        ctx_hi, ctx_lo, Bih_hi, Bih_lo, combo, WmT, WbT,
        midt, bott, c, hA_hi, hA_lo,
        hid_hi, hid_lo, s);
  }

  // out = hid @ W_gen^T + b_gen  (bf16x2), M = S*B = 13312, N=64 (n<38 kept)
  gemm_bf<64,64,2><<<dim3(1,208), 256, 10240, stream>>>(
      hid_hi, hid_lo, 512, Wg_hi, Wg_lo, 512,
      out, 0, bgen, 3, 16);
}